// Round 1
// baseline (629.434 us; speedup 1.0000x reference)
//
#include <hip/hip_runtime.h>
#include <hip/hip_bf16.h>

// Problem: B=4, N=4096, D_IN=D_OUT=512, all fp32 in/out.
// out[b,i,:] = (deg_i/r_i) * sum_j g(s_i+s_j)*mask[b,i,j] * y[b,j,:]
//   s = x @ (w@a)  (fp32 exact path)
//   y = x @ w      (bf16 MFMA)
//   g(t) = exp(leaky_0.1(8*tanh(t/8)))
// Workspace layout (bytes):
//   wT16:   0        .. 524288    bf16 w^T [512][512] (k contiguous)
//   v:      524288   .. 526336    fp32 [512]
//   s:      526336   .. 591872    fp32 [16384]
//   x16:    591872   .. 17369088  bf16 x [16384][512]
//   yT:     17369088 .. 34146304  bf16 y^T [512][16384]
// Requires ws_size >= 34146304.

typedef __attribute__((ext_vector_type(4))) float f32x4;
typedef __attribute__((ext_vector_type(8))) short short8;

#define NN 4096
#define DD 512
#define BN_TOT 16384  // B * N

__device__ __forceinline__ short f2bf(float f) {
    union { float f; unsigned u; } x;
    x.f = f;
    unsigned r = x.u + 0x7FFFu + ((x.u >> 16) & 1u);  // RTNE
    return (short)(r >> 16);
}

// g(t) = exp(leaky(8*tanh(t/8))); tanh(z) = 1 - 2/(exp(2z)+1); 2z = t/4.
// exp(inf)->inf -> rcp->0 -> c=8 ; exp(-inf)->0 -> c=-8. Saturation correct.
__device__ __forceinline__ float gfun(float t) {
    float e = __expf(t * 0.25f);
    float c = 8.0f - 16.0f * __builtin_amdgcn_rcpf(e + 1.0f);
    c = (c >= 0.0f) ? c : 0.1f * c;
    return __expf(c);
}

// K1a: wT16[d][k] = bf16(w[k][d])
__global__ __launch_bounds__(256) void k_wt(const float* __restrict__ w,
                                            short* __restrict__ wT) {
    int tid = blockIdx.x * 256 + threadIdx.x;  // 0..262143
    int d = tid >> 9, k = tid & 511;
    wT[tid] = f2bf(w[(size_t)k * 512 + d]);
}

// K1b: v[i] = sum_j w[i][j]*a[j]; one wave per i (512 waves)
__global__ __launch_bounds__(256) void k_v(const float* __restrict__ w,
                                           const float* __restrict__ a,
                                           float* __restrict__ v) {
    int gw = (blockIdx.x * 256 + threadIdx.x) >> 6;  // 0..511
    int l = threadIdx.x & 63;
    const float* row = w + (size_t)gw * 512 + l * 8;
    const float* ap = a + l * 8;
    float4 w0 = *(const float4*)(row);
    float4 w1 = *(const float4*)(row + 4);
    float4 a0 = *(const float4*)(ap);
    float4 a1 = *(const float4*)(ap + 4);
    float p = w0.x * a0.x + w0.y * a0.y + w0.z * a0.z + w0.w * a0.w +
              w1.x * a1.x + w1.y * a1.y + w1.z * a1.z + w1.w * a1.w;
#pragma unroll
    for (int off = 32; off > 0; off >>= 1) p += __shfl_down(p, off);
    if (l == 0) v[gw] = p;
}

// K2: s[row] = x[row]·v ; x16[row] = bf16(x[row]). One wave per row.
__global__ __launch_bounds__(256) void k_s_x16(const float* __restrict__ x,
                                               const float* __restrict__ v,
                                               float* __restrict__ s,
                                               short* __restrict__ x16) {
    __shared__ float vs[512];
    int t = threadIdx.x;
    vs[t] = v[t];
    vs[t + 256] = v[t + 256];
    __syncthreads();
    int w = t >> 6, l = t & 63;
    size_t row = (size_t)blockIdx.x * 4 + w;
    const float* xr = x + row * 512 + l * 8;
    float4 x0 = *(const float4*)(xr);
    float4 x1 = *(const float4*)(xr + 4);
    const float* vp = vs + l * 8;
    float p = x0.x * vp[0] + x0.y * vp[1] + x0.z * vp[2] + x0.w * vp[3] +
              x1.x * vp[4] + x1.y * vp[5] + x1.z * vp[6] + x1.w * vp[7];
    short8 pk;
    pk[0] = f2bf(x0.x); pk[1] = f2bf(x0.y); pk[2] = f2bf(x0.z); pk[3] = f2bf(x0.w);
    pk[4] = f2bf(x1.x); pk[5] = f2bf(x1.y); pk[6] = f2bf(x1.z); pk[7] = f2bf(x1.w);
    *(short8*)(x16 + row * 512 + l * 8) = pk;
#pragma unroll
    for (int off = 32; off > 0; off >>= 1) p += __shfl_down(p, off);
    if (l == 0) s[row] = p;
}

// K3: yT[d][bn] = sum_k wT16[d][k] * x16[bn][k]. GEMM-BT, 128x128 tile, BK=64.
// grid 512: mt = bx&3 (d-tiles), nt = bx>>2 (bn-tiles). 4 waves, wave tile 64x64.
__global__ __launch_bounds__(256, 2) void k_ygemm(const short* __restrict__ wT,
                                                  const short* __restrict__ x16,
                                                  short* __restrict__ yT) {
    __shared__ __align__(16) short At[128 * 72];
    __shared__ __align__(16) short Bt[128 * 72];
    const int t = threadIdx.x;
    const int w = t >> 6, l = t & 63;
    const int mt = blockIdx.x & 3, nt = blockIdx.x >> 2;
    const int wr = w >> 1, wc = w & 1;
    f32x4 acc[4][4];
#pragma unroll
    for (int i = 0; i < 4; ++i)
#pragma unroll
        for (int j = 0; j < 4; ++j) acc[i][j] = (f32x4){0.f, 0.f, 0.f, 0.f};

    const short* Ag = wT + (size_t)(mt * 128 + (t >> 3)) * 512 + (t & 7) * 8;
    const short* Bg = x16 + (size_t)(nt * 128 + (t >> 3)) * 512 + (t & 7) * 8;
    short* Aw = At + (t >> 3) * 72 + (t & 7) * 8;
    short* Bw = Bt + (t >> 3) * 72 + (t & 7) * 8;
    const short* Ar = At + (wr * 64 + (l & 15)) * 72 + (l >> 4) * 8;
    const short* Br = Bt + (wc * 64 + (l & 15)) * 72 + (l >> 4) * 8;

    for (int kk = 0; kk < 8; ++kk) {
        const int k0 = kk * 64;
        short8 va[4], vb[4];
#pragma unroll
        for (int ii = 0; ii < 4; ++ii) {
            va[ii] = *(const short8*)(Ag + (size_t)ii * 32 * 512 + k0);
            vb[ii] = *(const short8*)(Bg + (size_t)ii * 32 * 512 + k0);
        }
        __syncthreads();  // previous iter's frag reads complete
#pragma unroll
        for (int ii = 0; ii < 4; ++ii) {
            *(short8*)(Aw + ii * 32 * 72) = va[ii];
            *(short8*)(Bw + ii * 32 * 72) = vb[ii];
        }
        __syncthreads();
#pragma unroll
        for (int ks = 0; ks < 2; ++ks) {
            short8 af[4], bf[4];
#pragma unroll
            for (int it = 0; it < 4; ++it)
                af[it] = *(const short8*)(Ar + it * 16 * 72 + ks * 32);
#pragma unroll
            for (int jt = 0; jt < 4; ++jt)
                bf[jt] = *(const short8*)(Br + jt * 16 * 72 + ks * 32);
#pragma unroll
            for (int it = 0; it < 4; ++it)
#pragma unroll
                for (int jt = 0; jt < 4; ++jt)
                    acc[it][jt] = __builtin_amdgcn_mfma_f32_16x16x32_bf16(
                        af[it], bf[jt], acc[it][jt], 0, 0, 0);
        }
    }
    // C/D layout: col = lane&15, row = (lane>>4)*4 + reg
#pragma unroll
    for (int it = 0; it < 4; ++it)
#pragma unroll
        for (int jt = 0; jt < 4; ++jt)
#pragma unroll
            for (int r = 0; r < 4; ++r) {
                int drow = mt * 128 + wr * 64 + it * 16 + (l >> 4) * 4 + r;
                int bn = nt * 128 + wc * 64 + jt * 16 + (l & 15);
                yT[(size_t)drow * BN_TOT + bn] = f2bf(acc[it][jt][r]);
            }
}

// K4: fused mask pass. grid 512: b = bx>>7, i0 = (bx&127)*32.
// 256 threads = 4 waves; wave w owns d-slice [w*128, w*128+128).
// Per j-tile (64 wide): thread (i = t>>3, seg = t&7) generates 8 P elems,
// accumulates r/deg partials; P tile 32x64 bf16 in LDS (stride 72).
__global__ __launch_bounds__(256, 2) void k_fused(const float* __restrict__ mask,
                                                  const float* __restrict__ s,
                                                  const short* __restrict__ yT,
                                                  float* __restrict__ out) {
    __shared__ __align__(16) short P[32 * 72];
    __shared__ float scl[32];
    const int t = threadIdx.x;
    const int w = t >> 6, l = t & 63;
    const int b = blockIdx.x >> 7;
    const int i0 = (blockIdx.x & 127) << 5;
    const int i = t >> 3;
    const int seg = t & 7;
    const float s_i = s[b * NN + i0 + i];
    const float* mrow = mask + (size_t)(b * NN + i0 + i) * NN + seg * 8;
    const float* sb = s + b * NN + seg * 8;
    const short* yb = yT + (size_t)(w * 128 + (l & 15)) * BN_TOT + b * NN + ((l >> 4) * 8);
    short* pw = P + i * 72 + seg * 8;
    const short* pr = P + (l & 15) * 72 + (l >> 4) * 8;

    f32x4 acc[2][8];
#pragma unroll
    for (int a1 = 0; a1 < 2; ++a1)
#pragma unroll
        for (int a2 = 0; a2 < 8; ++a2) acc[a1][a2] = (f32x4){0.f, 0.f, 0.f, 0.f};
    float r_part = 0.f, deg_part = 0.f;

    for (int jt = 0; jt < 64; ++jt) {
        const int j0 = jt * 64;
        float4 m0 = *(const float4*)(mrow + j0);
        float4 m1 = *(const float4*)(mrow + j0 + 4);
        float4 sj0 = *(const float4*)(sb + j0);
        float4 sj1 = *(const float4*)(sb + j0 + 4);
        float mv[8] = {m0.x, m0.y, m0.z, m0.w, m1.x, m1.y, m1.z, m1.w};
        float sv[8] = {sj0.x, sj0.y, sj0.z, sj0.w, sj1.x, sj1.y, sj1.z, sj1.w};
        short8 pk;
#pragma unroll
        for (int e = 0; e < 8; ++e) {
            float p = gfun(s_i + sv[e]) * mv[e];
            deg_part += mv[e];
            r_part += p;
            pk[e] = f2bf(p);
        }
        *(short8*)pw = pk;
        __syncthreads();
#pragma unroll
        for (int ks = 0; ks < 2; ++ks) {
            short8 a0 = *(const short8*)(pr + ks * 32);
            short8 a1 = *(const short8*)(pr + 16 * 72 + ks * 32);
#pragma unroll
            for (int dt = 0; dt < 8; ++dt) {
                short8 bf = *(const short8*)(yb + (size_t)dt * 16 * BN_TOT + j0 + ks * 32);
                acc[0][dt] = __builtin_amdgcn_mfma_f32_16x16x32_bf16(a0, bf, acc[0][dt], 0, 0, 0);
                acc[1][dt] = __builtin_amdgcn_mfma_f32_16x16x32_bf16(a1, bf, acc[1][dt], 0, 0, 0);
            }
        }
        __syncthreads();
    }
    // reduce r/deg across the 8 seg-threads of each row (consecutive lanes)
#pragma unroll
    for (int off = 1; off < 8; off <<= 1) {
        r_part += __shfl_xor(r_part, off);
        deg_part += __shfl_xor(deg_part, off);
    }
    if (seg == 0) scl[i] = deg_part / r_part;
    __syncthreads();
    // epilogue: C/D layout col = lane&15 (d), row = (lane>>4)*4 + reg (i)
#pragma unroll
    for (int it = 0; it < 2; ++it)
#pragma unroll
        for (int r = 0; r < 4; ++r) {
            const int row = it * 16 + (l >> 4) * 4 + r;
            const float sc = scl[row];
            float* op = out + (size_t)(b * NN + i0 + row) * 512 + w * 128 + (l & 15);
#pragma unroll
            for (int dt = 0; dt < 8; ++dt) op[dt * 16] = acc[it][dt][r] * sc;
        }
}

extern "C" void kernel_launch(void* const* d_in, const int* in_sizes, int n_in,
                              void* d_out, int out_size, void* d_ws, size_t ws_size,
                              hipStream_t stream) {
    const float* x = (const float*)d_in[0];      // [4,4096,512]
    const float* mask = (const float*)d_in[1];   // [4,4096,4096]
    const float* w = (const float*)d_in[2];      // [512,512]
    const float* a = (const float*)d_in[3];      // [512]
    float* out = (float*)d_out;                  // [4,4096,512]
    char* ws = (char*)d_ws;
    short* wT = (short*)(ws);                    // 524288 B
    float* v = (float*)(ws + 524288);            // 2048 B
    float* s = (float*)(ws + 526336);            // 65536 B
    short* x16 = (short*)(ws + 591872);          // 16777216 B
    short* yT = (short*)(ws + 17369088);         // 16777216 B

    hipLaunchKernelGGL(k_wt, dim3(1024), dim3(256), 0, stream, w, wT);
    hipLaunchKernelGGL(k_v, dim3(128), dim3(256), 0, stream, w, a, v);
    hipLaunchKernelGGL(k_s_x16, dim3(4096), dim3(256), 0, stream, x, v, s, x16);
    hipLaunchKernelGGL(k_ygemm, dim3(512), dim3(256), 0, stream, wT, x16, yT);
    hipLaunchKernelGGL(k_fused, dim3(512), dim3(256), 0, stream, mask, s, yT, out);
}

// Round 2
// 584.589 us; speedup vs baseline: 1.0767x; 1.0767x over previous
//
#include <hip/hip_runtime.h>
#include <hip/hip_bf16.h>

// Problem: B=4, N=4096, D_IN=D_OUT=512, all fp32 in/out.
// out[b,i,:] = (deg_i/r_i) * sum_j g(s_i+s_j)*mask[b,i,j] * y[b,j,:]
//   s = x @ (w@a)  (fp32 exact path)
//   y = x @ w      (bf16 MFMA)
//   g(t) = exp(leaky_0.1(8*tanh(t/8)))
// Workspace layout (bytes):
//   wT16:   0        .. 524288    bf16 w^T [512][512] (k contiguous)
//   v:      524288   .. 526336    fp32 [512]
//   s:      526336   .. 591872    fp32 [16384]
//   x16:    591872   .. 17369088  bf16 x [16384][512]
//   yT:     17369088 .. 34146304  bf16 y^T [512][16384]
// Requires ws_size >= 34146304.

typedef __attribute__((ext_vector_type(4))) float f32x4;
typedef __attribute__((ext_vector_type(8))) short short8;

#define NN 4096
#define DD 512
#define BN_TOT 16384  // B * N

__device__ __forceinline__ short f2bf(float f) {
    union { float f; unsigned u; } x;
    x.f = f;
    unsigned r = x.u + 0x7FFFu + ((x.u >> 16) & 1u);  // RTNE
    return (short)(r >> 16);
}

// g(t) = exp(leaky(8*tanh(t/8))); tanh(z) = 1 - 2/(exp(2z)+1); 2z = t/4.
__device__ __forceinline__ float gfun(float t) {
    float e = __expf(t * 0.25f);
    float c = 8.0f - 16.0f * __builtin_amdgcn_rcpf(e + 1.0f);
    c = (c >= 0.0f) ? c : 0.1f * c;
    return __expf(c);
}

// K1a: wT16[d][k] = bf16(w[k][d])
__global__ __launch_bounds__(256) void k_wt(const float* __restrict__ w,
                                            short* __restrict__ wT) {
    int tid = blockIdx.x * 256 + threadIdx.x;  // 0..262143
    int d = tid >> 9, k = tid & 511;
    wT[tid] = f2bf(w[(size_t)k * 512 + d]);
}

// K1b: v[i] = sum_j w[i][j]*a[j]; one wave per i (512 waves)
__global__ __launch_bounds__(256) void k_v(const float* __restrict__ w,
                                           const float* __restrict__ a,
                                           float* __restrict__ v) {
    int gw = (blockIdx.x * 256 + threadIdx.x) >> 6;  // 0..511
    int l = threadIdx.x & 63;
    const float* row = w + (size_t)gw * 512 + l * 8;
    const float* ap = a + l * 8;
    float4 w0 = *(const float4*)(row);
    float4 w1 = *(const float4*)(row + 4);
    float4 a0 = *(const float4*)(ap);
    float4 a1 = *(const float4*)(ap + 4);
    float p = w0.x * a0.x + w0.y * a0.y + w0.z * a0.z + w0.w * a0.w +
              w1.x * a1.x + w1.y * a1.y + w1.z * a1.z + w1.w * a1.w;
#pragma unroll
    for (int off = 32; off > 0; off >>= 1) p += __shfl_down(p, off);
    if (l == 0) v[gw] = p;
}

// K2: s[row] = x[row]·v ; x16[row] = bf16(x[row]). One wave per row.
__global__ __launch_bounds__(256) void k_s_x16(const float* __restrict__ x,
                                               const float* __restrict__ v,
                                               float* __restrict__ s,
                                               short* __restrict__ x16) {
    __shared__ float vs[512];
    int t = threadIdx.x;
    vs[t] = v[t];
    vs[t + 256] = v[t + 256];
    __syncthreads();
    int w = t >> 6, l = t & 63;
    size_t row = (size_t)blockIdx.x * 4 + w;
    const float* xr = x + row * 512 + l * 8;
    float4 x0 = *(const float4*)(xr);
    float4 x1 = *(const float4*)(xr + 4);
    const float* vp = vs + l * 8;
    float p = x0.x * vp[0] + x0.y * vp[1] + x0.z * vp[2] + x0.w * vp[3] +
              x1.x * vp[4] + x1.y * vp[5] + x1.z * vp[6] + x1.w * vp[7];
    short8 pk;
    pk[0] = f2bf(x0.x); pk[1] = f2bf(x0.y); pk[2] = f2bf(x0.z); pk[3] = f2bf(x0.w);
    pk[4] = f2bf(x1.x); pk[5] = f2bf(x1.y); pk[6] = f2bf(x1.z); pk[7] = f2bf(x1.w);
    *(short8*)(x16 + row * 512 + l * 8) = pk;
#pragma unroll
    for (int off = 32; off > 0; off >>= 1) p += __shfl_down(p, off);
    if (l == 0) s[row] = p;
}

// K3: yT[d][bn] = sum_k wT16[d][k] * x16[bn][k]. GEMM-BT, 128x128 tile, BK=64.
// Prefetch next kk's global loads under the MFMA phase.
__global__ __launch_bounds__(256, 2) void k_ygemm(const short* __restrict__ wT,
                                                  const short* __restrict__ x16,
                                                  short* __restrict__ yT) {
    __shared__ __align__(16) short At[128 * 72];
    __shared__ __align__(16) short Bt[128 * 72];
    const int t = threadIdx.x;
    const int w = t >> 6, l = t & 63;
    const int mt = blockIdx.x & 3, nt = blockIdx.x >> 2;
    const int wr = w >> 1, wc = w & 1;
    f32x4 acc[4][4];
#pragma unroll
    for (int i = 0; i < 4; ++i)
#pragma unroll
        for (int j = 0; j < 4; ++j) acc[i][j] = (f32x4){0.f, 0.f, 0.f, 0.f};

    const short* Ag = wT + (size_t)(mt * 128 + (t >> 3)) * 512 + (t & 7) * 8;
    const short* Bg = x16 + (size_t)(nt * 128 + (t >> 3)) * 512 + (t & 7) * 8;
    short* Aw = At + (t >> 3) * 72 + (t & 7) * 8;
    short* Bw = Bt + (t >> 3) * 72 + (t & 7) * 8;
    const short* Ar = At + (wr * 64 + (l & 15)) * 72 + (l >> 4) * 8;
    const short* Br = Bt + (wc * 64 + (l & 15)) * 72 + (l >> 4) * 8;

    short8 va[4], vb[4];
#pragma unroll
    for (int ii = 0; ii < 4; ++ii) {
        va[ii] = *(const short8*)(Ag + (size_t)ii * 32 * 512);
        vb[ii] = *(const short8*)(Bg + (size_t)ii * 32 * 512);
    }

    for (int kk = 0; kk < 8; ++kk) {
        __syncthreads();  // previous iter's frag reads complete
#pragma unroll
        for (int ii = 0; ii < 4; ++ii) {
            *(short8*)(Aw + ii * 32 * 72) = va[ii];
            *(short8*)(Bw + ii * 32 * 72) = vb[ii];
        }
        __syncthreads();
        if (kk < 7) {
            const int k0 = (kk + 1) * 64;
#pragma unroll
            for (int ii = 0; ii < 4; ++ii) {
                va[ii] = *(const short8*)(Ag + (size_t)ii * 32 * 512 + k0);
                vb[ii] = *(const short8*)(Bg + (size_t)ii * 32 * 512 + k0);
            }
        }
#pragma unroll
        for (int ks = 0; ks < 2; ++ks) {
            short8 af[4], bfr[4];
#pragma unroll
            for (int it = 0; it < 4; ++it)
                af[it] = *(const short8*)(Ar + it * 16 * 72 + ks * 32);
#pragma unroll
            for (int jt = 0; jt < 4; ++jt)
                bfr[jt] = *(const short8*)(Br + jt * 16 * 72 + ks * 32);
#pragma unroll
            for (int it = 0; it < 4; ++it)
#pragma unroll
                for (int jt = 0; jt < 4; ++jt)
                    acc[it][jt] = __builtin_amdgcn_mfma_f32_16x16x32_bf16(
                        af[it], bfr[jt], acc[it][jt], 0, 0, 0);
        }
    }
    // C/D layout: col = lane&15, row = (lane>>4)*4 + reg
#pragma unroll
    for (int it = 0; it < 4; ++it)
#pragma unroll
        for (int jt = 0; jt < 4; ++jt)
#pragma unroll
            for (int r = 0; r < 4; ++r) {
                int drow = mt * 128 + wr * 64 + it * 16 + (l >> 4) * 4 + r;
                int bn = nt * 128 + wc * 64 + jt * 16 + (l & 15);
                yT[(size_t)drow * BN_TOT + bn] = f2bf(acc[it][jt][r]);
            }
}

// K4: fused mask pass. grid 512: b = bx>>7, i0 = (bx&127)*32.
// 256 threads = 4 waves; wave w owns d-slice [w*128, w*128+128).
// Pipelined: mask/s prefetched 1 iter ahead; all 16 yT B-frags batched into
// regs pre-barrier (independent of LDS); P double-buffered -> 1 barrier/iter.
__global__ __launch_bounds__(256, 2) void k_fused(const float* __restrict__ mask,
                                                  const float* __restrict__ s,
                                                  const short* __restrict__ yT,
                                                  float* __restrict__ out) {
    __shared__ __align__(16) short P[2][32 * 72];
    __shared__ float scl[32];
    const int t = threadIdx.x;
    const int w = t >> 6, l = t & 63;
    const int b = blockIdx.x >> 7;
    const int i0 = (blockIdx.x & 127) << 5;
    const int i = t >> 3;
    const int seg = t & 7;
    const float s_i = s[b * NN + i0 + i];
    const float* mrow = mask + (size_t)(b * NN + i0 + i) * NN + seg * 8;
    const float* sb = s + b * NN + seg * 8;
    const short* ybase = yT + (size_t)(w * 128 + (l & 15)) * BN_TOT + b * NN + ((l >> 4) * 8);
    const int pwoff = i * 72 + seg * 8;
    const int proff = (l & 15) * 72 + (l >> 4) * 8;

    f32x4 acc[2][8];
#pragma unroll
    for (int a1 = 0; a1 < 2; ++a1)
#pragma unroll
        for (int a2 = 0; a2 < 8; ++a2) acc[a1][a2] = (f32x4){0.f, 0.f, 0.f, 0.f};
    float r_part = 0.f, deg_part = 0.f;

    // prefetch iter 0 mask/s
    float4 m0 = *(const float4*)(mrow);
    float4 m1 = *(const float4*)(mrow + 4);
    float4 sj0 = *(const float4*)(sb);
    float4 sj1 = *(const float4*)(sb + 4);

    for (int jt = 0; jt < 64; ++jt) {
        const int buf = jt & 1;
        // consume prefetch into locals (so next prefetch can reuse regs)
        float mv[8] = {m0.x, m0.y, m0.z, m0.w, m1.x, m1.y, m1.z, m1.w};
        float sv[8] = {sj0.x, sj0.y, sj0.z, sj0.w, sj1.x, sj1.y, sj1.z, sj1.w};

        // batch-issue all 16 B-frag loads for THIS iter (independent of LDS)
        short8 bfr[16];
        const short* yb = ybase + jt * 64;
#pragma unroll
        for (int ks = 0; ks < 2; ++ks)
#pragma unroll
            for (int dt = 0; dt < 8; ++dt)
                bfr[ks * 8 + dt] =
                    *(const short8*)(yb + (size_t)dt * 16 * BN_TOT + ks * 32);

        // issue mask/s prefetch for jt+1
        if (jt < 63) {
            const int j0n = (jt + 1) * 64;
            m0 = *(const float4*)(mrow + j0n);
            m1 = *(const float4*)(mrow + j0n + 4);
            sj0 = *(const float4*)(sb + j0n);
            sj1 = *(const float4*)(sb + j0n + 4);
        }

        // gfun + P write (overlaps the in-flight global loads)
        short8 pk;
#pragma unroll
        for (int e = 0; e < 8; ++e) {
            float p = gfun(s_i + sv[e]) * mv[e];
            deg_part += mv[e];
            r_part += p;
            pk[e] = f2bf(p);
        }
        *(short8*)(P[buf] + pwoff) = pk;

        __syncthreads();  // single barrier: P[buf] visible; prev-buf reads drained

        // MFMA phase: A from LDS, B from the batched regs
#pragma unroll
        for (int ks = 0; ks < 2; ++ks) {
            short8 a0 = *(const short8*)(P[buf] + proff + ks * 32);
            short8 a1 = *(const short8*)(P[buf] + proff + 16 * 72 + ks * 32);
#pragma unroll
            for (int dt = 0; dt < 8; ++dt) {
                acc[0][dt] = __builtin_amdgcn_mfma_f32_16x16x32_bf16(
                    a0, bfr[ks * 8 + dt], acc[0][dt], 0, 0, 0);
                acc[1][dt] = __builtin_amdgcn_mfma_f32_16x16x32_bf16(
                    a1, bfr[ks * 8 + dt], acc[1][dt], 0, 0, 0);
            }
        }
    }
    // reduce r/deg across the 8 seg-threads of each row (consecutive lanes)
#pragma unroll
    for (int off = 1; off < 8; off <<= 1) {
        r_part += __shfl_xor(r_part, off);
        deg_part += __shfl_xor(deg_part, off);
    }
    if (seg == 0) scl[i] = deg_part / r_part;
    __syncthreads();
    // epilogue: C/D layout col = lane&15 (d), row = (lane>>4)*4 + reg (i)
#pragma unroll
    for (int it = 0; it < 2; ++it)
#pragma unroll
        for (int r = 0; r < 4; ++r) {
            const int row = it * 16 + (l >> 4) * 4 + r;
            const float sc = scl[row];
            float* op = out + (size_t)(b * NN + i0 + row) * 512 + w * 128 + (l & 15);
#pragma unroll
            for (int dt = 0; dt < 8; ++dt) op[dt * 16] = acc[it][dt][r] * sc;
        }
}

extern "C" void kernel_launch(void* const* d_in, const int* in_sizes, int n_in,
                              void* d_out, int out_size, void* d_ws, size_t ws_size,
                              hipStream_t stream) {
    const float* x = (const float*)d_in[0];      // [4,4096,512]
    const float* mask = (const float*)d_in[1];   // [4,4096,4096]
    const float* w = (const float*)d_in[2];      // [512,512]
    const float* a = (const float*)d_in[3];      // [512]
    float* out = (float*)d_out;                  // [4,4096,512]
    char* ws = (char*)d_ws;
    short* wT = (short*)(ws);                    // 524288 B
    float* v = (float*)(ws + 524288);            // 2048 B
    float* s = (float*)(ws + 526336);            // 65536 B
    short* x16 = (short*)(ws + 591872);          // 16777216 B
    short* yT = (short*)(ws + 17369088);         // 16777216 B

    hipLaunchKernelGGL(k_wt, dim3(1024), dim3(256), 0, stream, w, wT);
    hipLaunchKernelGGL(k_v, dim3(128), dim3(256), 0, stream, w, a, v);
    hipLaunchKernelGGL(k_s_x16, dim3(4096), dim3(256), 0, stream, x, v, s, x16);
    hipLaunchKernelGGL(k_ygemm, dim3(512), dim3(256), 0, stream, wT, x16, yT);
    hipLaunchKernelGGL(k_fused, dim3(512), dim3(256), 0, stream, mask, s, yT, out);
}